// Round 3
// baseline (15.546 us; speedup 1.0000x reference)
//
#include <hip/hip_runtime.h>

namespace {
constexpr int IC = 8, IH = 28, IW = 28;
constexpr int OC = 16, KH = 3, KW = 3;
constexpr int OH = 28, OW = 28;
constexpr int BATCH = 64;
constexpr int XIN  = IC * IH * IW;   // 6272
constexpr int XOUT = OC * OH * OW;   // 12544
constexpr int PIH = 30;              // 28 + 2 halo rows
constexpr int RSTRIDE = 32;          // padded row stride (floats) -> aligned b128 reads
constexpr int CSZ = PIH * RSTRIDE;   // 960 floats per channel
constexpr int PSZ = IC * CSZ;        // 7680 floats = 30.7 KB
constexpr int THREADS = 256;
constexpr int NV4 = XIN / 4;         // 1568 float4 per image
}

// XOR-swizzle: rows are stride-32 (power of 2), so same-column reads across rows
// would hit the same banks. XOR the 4-float group index with (row&7) -> per-bank
// load is uniform (8 accesses/bank for a wave's b128 = the 1KB/8cyc floor).
// Group-internal offset (bits 0-1) untouched, so 16B-aligned float4s stay intact.
__device__ __forceinline__ int swz(int row, int col) {   // col 0..29
    return (row << 5) | (col & 3) | ((((col >> 2) ^ row) & 7) << 2);
}

// weight is the Toeplitz expansion of a 16x8x3x3 conv kernel (stride 1, pad 1):
// kernel[oc,ic,ky,kx] = weight[oc*784 + 406, ic*784 + (13+ky)*28 + (13+kx)].
// Tap addresses are block-uniform -> compiler emits s_load, taps live in SGPRs.
__global__ __launch_bounds__(THREADS) void conv2d_toeplitz_kernel(
    const float* __restrict__ x, const float* __restrict__ w,
    const float* __restrict__ bias, float* __restrict__ out)
{
    __shared__ __align__(16) float xs[PSZ];

    const int tid = threadIdx.x;
    const int b   = blockIdx.x >> 4;   // 64 batches
    const int oc  = blockIdx.x & 15;   // 16 output channels

    // ---- issue x loads first (latency hides under tap s_loads + halo zero) ----
    const float4* xb4 = reinterpret_cast<const float4*>(x + b * XIN);
    float4 v[7];
    #pragma unroll
    for (int k = 0; k < 7; ++k) {
        int i = tid + k * THREADS;
        if (i < NV4) v[k] = xb4[i];
    }

    // ---- taps + bias via block-uniform (scalar) loads ----
    float kt[IC * KH * KW];
    {
        const float* wrow = w + (long)(oc * (OH * OW) + 14 * OW + 14) * XIN;
        #pragma unroll
        for (int ic = 0; ic < IC; ++ic)
            #pragma unroll
            for (int ky = 0; ky < KH; ++ky)
                #pragma unroll
                for (int kx = 0; kx < KW; ++kx)
                    kt[ic * 9 + ky * 3 + kx] =
                        wrow[ic * (IH * IW) + (13 + ky) * IW + (13 + kx)];
    }
    const float bsv = bias[oc * (OH * OW)];

    // ---- zero ONLY the halo (disjoint from interior: no extra barrier) ----
    // 116 halo cells per channel: rows 0/29 full (60), cols 0/29 rows 1..28 (56)
    for (int i = tid; i < IC * 116; i += THREADS) {
        int ic = i / 116;
        int h  = i - ic * 116;
        int row, col;
        if (h < 60)      { row = (h < 30) ? 0 : 29; col = (h < 30) ? h : h - 30; }
        else if (h < 88) { row = h - 59; col = 0; }
        else             { row = h - 87; col = 29; }
        xs[ic * CSZ + swz(row, col)] = 0.0f;
    }

    // ---- write staged image into padded interior (swizzled scalar writes) ----
    #pragma unroll
    for (int k = 0; k < 7; ++k) {
        int i = tid + k * THREADS;
        if (i < NV4) {
            int ic  = i / 196;            // 196 float4 per channel
            int r   = i - ic * 196;
            int row = r / 7 + 1;          // padded row
            int cf  = (r - (r / 7) * 7) * 4 + 1;  // padded col of elem 0
            float* cb = &xs[ic * CSZ];
            cb[swz(row, cf + 0)] = v[k].x;
            cb[swz(row, cf + 1)] = v[k].y;
            cb[swz(row, cf + 2)] = v[k].z;
            cb[swz(row, cf + 3)] = v[k].w;
        }
    }

    __syncthreads();   // the ONLY barrier

    // ---- 196 threads x 4 consecutive outputs (28 = 7 groups of 4) ----
    if (tid < 196) {
        const int oy = tid / 7;
        const int ox = (tid - oy * 7) * 4;   // padded col of first window elem
        const int g  = ox >> 2;
        float a0 = bsv, a1 = bsv, a2 = bsv, a3 = bsv;
        #pragma unroll
        for (int ic = 0; ic < IC; ++ic) {
            #pragma unroll
            for (int ky = 0; ky < KH; ++ky) {
                const int row = oy + ky;
                const int r7  = row & 7;
                const float* base = &xs[ic * CSZ + (row << 5)];
                const float4 g0 = *reinterpret_cast<const float4*>(&base[(g ^ r7) << 2]);
                const float2 g1 = *reinterpret_cast<const float2*>(&base[((g + 1) ^ r7) << 2]);
                const float x0 = g0.x, x1 = g0.y, x2 = g0.z, x3 = g0.w;
                const float x4 = g1.x, x5 = g1.y;
                const float k0 = kt[ic * 9 + ky * 3 + 0];
                const float k1 = kt[ic * 9 + ky * 3 + 1];
                const float k2 = kt[ic * 9 + ky * 3 + 2];
                a0 = fmaf(x2, k2, fmaf(x1, k1, fmaf(x0, k0, a0)));
                a1 = fmaf(x3, k2, fmaf(x2, k1, fmaf(x1, k0, a1)));
                a2 = fmaf(x4, k2, fmaf(x3, k1, fmaf(x2, k0, a2)));
                a3 = fmaf(x5, k2, fmaf(x4, k1, fmaf(x3, k0, a3)));
            }
        }
        // out index: b*12544 + oc*784 + oy*28 + ox; ox % 4 == 0 -> 16B aligned
        float4* op = reinterpret_cast<float4*>(
            out + (long)b * XOUT + oc * (OH * OW) + oy * OW + ox);
        *op = make_float4(a0, a1, a2, a3);
    }
}

extern "C" void kernel_launch(void* const* d_in, const int* in_sizes, int n_in,
                              void* d_out, int out_size, void* d_ws, size_t ws_size,
                              hipStream_t stream) {
    const float* x    = (const float*)d_in[0];   // enc_x  [64, 6272] f32
    const float* w    = (const float*)d_in[1];   // weight [12544, 6272] f32 (Toeplitz)
    const float* bias = (const float*)d_in[2];   // bias   [12544] f32 (repeat per oc)
    float* out = (float*)d_out;                  // [64, 12544] f32

    conv2d_toeplitz_kernel<<<dim3(BATCH * OC), THREADS, 0, stream>>>(x, w, bias, out);
}